// Round 17
// baseline (216.474 us; speedup 1.0000x reference)
//
#include <hip/hip_runtime.h>
#include <hip/hip_bf16.h>
#include <stdint.h>

#define BN 4
#define CN 128
#define HN 96
#define WN 96
#define HW (HN*WN)
#define OCN 128
#define OFFC 18
#define EPSV 1e-6f
#define HP 98
#define WP 98
#define NWG (BN*HN*3)

typedef __attribute__((ext_vector_type(8))) short bf16x8;
typedef __attribute__((ext_vector_type(4))) float f32x4;

__device__ __forceinline__ float lo16(uint32_t u) {
  union { uint32_t i; float f; } v; v.i = u << 16; return v.f;
}
__device__ __forceinline__ float hi16(uint32_t u) {
  union { uint32_t i; float f; } v; v.i = u & 0xffff0000u; return v.f;
}
__device__ __forceinline__ uint16_t f2b(float f) {
  union { float f; uint32_t i; } u; u.f = f;
  uint32_t r = u.i + 0x7fffu + ((u.i >> 16) & 1u);   // RNE
  return (uint16_t)(r >> 16);
}
__device__ __forceinline__ uint32_t pk2(float a, float b) {
  return (uint32_t)f2b(a) | ((uint32_t)f2b(b) << 16);
}
__device__ __forceinline__ int swz(int row, int c) { return c ^ ((row & 7) << 3); }

__device__ __align__(16) uint16_t g_def[9 * 128 * 128];   // [k][oc][c]
__device__ __align__(16) uint16_t g_pw[128 * 128];        // [oc][c]
__device__ __align__(16) uint16_t g_off[32 * 1152];       // [j(pad32)][kk*128+c]
__device__ __align__(16) uint16_t g_xp[(size_t)BN * HP * WP * CN];  // channels-last, padded

__global__ __launch_bounds__(256)
void k_prep_w(const float* __restrict__ w_def, const float* __restrict__ w_pw,
              const float* __restrict__ w_off) {
  int i = blockIdx.x * 256 + threadIdx.x;
  if (i < 147456) {
    int k = i >> 14, rem = i & 16383, oc = rem >> 7, c = rem & 127;
    g_def[i] = f2b(w_def[((oc << 7) + c) * 9 + k]);
  } else if (i < 147456 + 16384) {
    int j = i - 147456;
    g_pw[j] = f2b(w_pw[j]);
  } else if (i < 147456 + 16384 + 36864) {
    int j = i - 163840;
    int row = j / 1152, col = j - row * 1152;
    int kk = col >> 7, c = col & 127;
    g_off[j] = (row < OFFC) ? f2b(w_off[((row << 7) + c) * 9 + kk]) : (uint16_t)0;
  }
}

__global__ __launch_bounds__(256)
void k_prep_x(const float* __restrict__ x) {
  __shared__ uint16_t trans[96][136];
  int blk = blockIdx.x;
  int y1 = blk % HP;
  int b  = blk / HP;
  int t = (int)threadIdx.x;
  uint16_t* dst = g_xp + ((size_t)(b * HP + y1) * WP) * CN;
  if (y1 == 0 || y1 == HP - 1) {
    for (int i = t; i < WP * CN / 8; i += 256)
      ((uint4*)dst)[i] = make_uint4(0, 0, 0, 0);
    return;
  }
  int y = y1 - 1;
  for (int i = t; i < CN * WN / 4; i += 256) {
    int c = i / 24, xq = i - c * 24;
    float4 f = *(const float4*)&x[((size_t)(b * CN + c) * HN + y) * WN + xq * 4];
    trans[xq * 4 + 0][c] = f2b(f.x);
    trans[xq * 4 + 1][c] = f2b(f.y);
    trans[xq * 4 + 2][c] = f2b(f.z);
    trans[xq * 4 + 3][c] = f2b(f.w);
  }
  __syncthreads();
  for (int i = t; i < 2 * CN / 8; i += 256) {
    int side = i >> 4, j = i & 15;
    ((uint4*)(dst + (size_t)side * (WP - 1) * CN))[j] = make_uint4(0, 0, 0, 0);
  }
  for (int i = t; i < WN * CN / 8; i += 256) {
    int xw = i >> 4, cq = (i & 15) * 8;
    ((uint4*)(dst + CN))[i] = *(const uint4*)&trans[xw][cq];
  }
}

// K-split fused kernel: deform taps are barrier-free (wave-private samples).
__global__ __launch_bounds__(256)
void k_fused(const float* __restrict__ b_off, const float* __restrict__ b_def,
             const float* __restrict__ ln_w, const float* __restrict__ ln_b,
             const float* __restrict__ w_dw, const float* __restrict__ b_dw,
             const float* __restrict__ b_pw, float* __restrict__ out) {
  // patch arena (26112B): phase A..B holds x-patch [3][34][128] swizzled.
  // After barrier 2: private samp bufs: 2 bufs x 4 waves x 32px x 40u16(80B rows)
  //   = 10240 u16 (20KB). After taps + barrier: redbuf f32[128][33] (16.9KB).
  __shared__ __align__(16) uint16_t patch[13056];
  __shared__ __align__(16) uint16_t dwT[4096];
  __shared__ float offarena[576];
  float (*offl)[32] = (float (*)[32])offarena;
  float (*red1)[32] = (float (*)[32])offarena;
  float (*red2)[32] = (float (*)[32])(offarena + 128);
  float* muv = offarena + 256;
  float* rsv = offarena + 288;
  float* redbuf = (float*)patch;              // 128*33 f32

  int bid = blockIdx.x;
  int wid = (bid & 7) * 144 + (bid >> 3);     // XCD-chunked swizzle
  int wt = wid % 3;
  int h  = (wid / 3) % HN;
  int b  = wid / (3 * HN);
  int w0 = wt * 32;

  int t = (int)threadIdx.x;
  int l = t & 63, w = t >> 6;
  int g = l >> 4, fr = l & 15;
  int p = t & 31, cg = t >> 5;
  const uint16_t* xb = g_xp + (size_t)b * HP * WP * CN;
  int cbase = w * 32 + (l & 3) * 8;           // this lane's global 8-ch chunk
  const uint16_t* bp = xb + cbase;
  uint16_t* sbuf0 = patch + w * 1280;         // wave-private, 80B rows
  uint16_t* sbuf1 = patch + 5120 + w * 1280;

  // ---- phase A: stage 3x34 pixel-records -> patch (r11 verbatim) -----------
  #pragma unroll
  for (int rep = 0; rep < 7; ++rep) {
    int e = t + 256 * rep;
    if (e < 1632) {
      int rec = e >> 4, chunk = e & 15;
      int ky = rec / 34, i = rec - 34 * ky;
      const uint16_t* src = xb + ((size_t)(h + ky) * WP + (w0 + i)) * CN + chunk * 8;
      *(uint4*)&patch[((ky * 34 + i) << 7) + swz(i, chunk * 8)] = *(const uint4*)src;
    }
  }
  __syncthreads();                            // barrier 1

  // ---- phase B1: offsets conv MFMA (r11 verbatim) --------------------------
  {
    int toc = w >> 1, tp = w & 1;
    f32x4 aco = {0.f, 0.f, 0.f, 0.f};
    #pragma unroll
    for (int ks = 0; ks < 36; ++ks) {
      int kk = ks >> 2;
      int ky = kk / 3, kx = kk - 3 * ky;
      int cb = ((ks & 3) << 5) + (g << 3);
      int i = fr + (tp << 4) + kx;
      bf16x8 a = *(const bf16x8*)&g_off[(toc * 16 + fr) * 1152 + (ks << 5) + (g << 3)];
      bf16x8 bb = *(const bf16x8*)&patch[((ky * 34 + i) << 7) + swz(i, cb)];
      aco = __builtin_amdgcn_mfma_f32_16x16x32_bf16(a, bb, aco, 0, 0, 0);
    }
    #pragma unroll
    for (int reg = 0; reg < 4; ++reg) {
      int j = toc * 16 + g * 4 + reg;
      if (j < OFFC) offl[j][(tp << 4) + fr] = aco[reg] + b_off[j];
    }
  }

  // ---- phase B2: depthwise 3x3 + residual -> regs (r11 verbatim) -----------
  float adw[16];
  {
    #pragma unroll
    for (int cl = 0; cl < 16; ++cl) adw[cl] = b_dw[cg * 16 + cl];
    #pragma unroll
    for (int ky = 0; ky < 3; ++ky) {
      #pragma unroll
      for (int kx = 0; kx < 3; ++kx) {
        int i = p + kx;
        uint32_t r[8];
        *(uint4*)&r[0] = *(const uint4*)&patch[((ky * 34 + i) << 7) + swz(i, cg * 16)];
        *(uint4*)&r[4] = *(const uint4*)&patch[((ky * 34 + i) << 7) + swz(i, cg * 16 + 8)];
        #pragma unroll
        for (int c2 = 0; c2 < 8; ++c2) {
          adw[2 * c2]     += lo16(r[c2]) * w_dw[(cg * 16 + 2 * c2) * 9 + ky * 3 + kx];
          adw[2 * c2 + 1] += hi16(r[c2]) * w_dw[(cg * 16 + 2 * c2 + 1) * 9 + ky * 3 + kx];
        }
      }
    }
    int i = p + 1;
    uint32_t r[8];
    *(uint4*)&r[0] = *(const uint4*)&patch[((34 + i) << 7) + swz(i, cg * 16)];
    *(uint4*)&r[4] = *(const uint4*)&patch[((34 + i) << 7) + swz(i, cg * 16 + 8)];
    #pragma unroll
    for (int c2 = 0; c2 < 8; ++c2) {
      adw[2 * c2]     += lo16(r[c2]);
      adw[2 * c2 + 1] += hi16(r[c2]);
    }
  }
  __syncthreads();    // barrier 2: patch reads done -> samp arena writable

  // wave-private gather: channels [32w,32w+32) for all 32 px, 80B padded rows
  auto GATHER = [&](int kk, uint16_t* wb) {
    int ky = kk / 3, kx = kk - 3 * ky;
    int chunk = l & 3;
    #pragma unroll
    for (int half = 0; half < 2; ++half) {
      int px = half * 16 + (l >> 2);
      float dy = offl[2 * kk][px], dx = offl[2 * kk + 1][px];
      float ys = (float)(h - 1 + ky) + dy;
      float xs = (float)(w0 + px - 1 + kx) + dx;
      float y0f = floorf(ys), x0f = floorf(xs);
      float fy = ys - y0f, fx = xs - x0f;
      int y0 = (int)y0f, x0 = (int)x0f;
      float w00 = (1.f - fy) * (1.f - fx), w01 = (1.f - fy) * fx;
      float w10 = fy * (1.f - fx),         w11 = fy * fx;
      bool yok0 = (y0 >= 0) & (y0 < HN), yok1 = (y0 + 1 >= 0) & (y0 + 1 < HN);
      bool xok0 = (x0 >= 0) & (x0 < WN), xok1 = (x0 + 1 >= 0) & (x0 + 1 < WN);
      if (!(yok0 & xok0)) w00 = 0.f;
      if (!(yok0 & xok1)) w01 = 0.f;
      if (!(yok1 & xok0)) w10 = 0.f;
      if (!(yok1 & xok1)) w11 = 0.f;
      int ya  = min(max(y0, -1), HN) + 1;
      int yb2 = min(max(y0 + 1, -1), HN) + 1;
      int xa  = min(max(x0, -1), WN) + 1;
      int xc2 = min(max(x0 + 1, -1), WN) + 1;
      uint32_t A[4], B[4], C[4], D[4];
      *(uint4*)A = *(const uint4*)(bp + ((size_t)ya * WP + xa) * CN);
      *(uint4*)B = *(const uint4*)(bp + ((size_t)ya * WP + xc2) * CN);
      *(uint4*)C = *(const uint4*)(bp + ((size_t)yb2 * WP + xa) * CN);
      *(uint4*)D = *(const uint4*)(bp + ((size_t)yb2 * WP + xc2) * CN);
      uint32_t pk4[4];
      #pragma unroll
      for (int q2 = 0; q2 < 4; ++q2) {
        float s0 = w00 * lo16(A[q2]) + w01 * lo16(B[q2]) + w10 * lo16(C[q2]) + w11 * lo16(D[q2]);
        float s1 = w00 * hi16(A[q2]) + w01 * hi16(B[q2]) + w10 * hi16(C[q2]) + w11 * hi16(D[q2]);
        pk4[q2] = pk2(s0, s1);
      }
      *(uint4*)&wb[px * 40 + chunk * 8] = *(uint4*)pk4;   // wave-private write
    }
  };

  // K-split tap MFMA: this wave's 32 channels, ALL 128 oc x 32 px partials
  f32x4 acc[8][2];
  #pragma unroll
  for (int r = 0; r < 8; ++r)
    #pragma unroll
    for (int q2 = 0; q2 < 2; ++q2) acc[r][q2] = (f32x4){0.f, 0.f, 0.f, 0.f};
  auto TAPMM = [&](int k, const uint16_t* rb) {
    const uint16_t* gdk = g_def + (k << 14) + w * 32 + g * 8;
    bf16x8 b0 = *(const bf16x8*)&rb[fr * 40 + g * 8];
    bf16x8 b1 = *(const bf16x8*)&rb[(16 + fr) * 40 + g * 8];
    #pragma unroll
    for (int r = 0; r < 8; ++r) {
      bf16x8 a = *(const bf16x8*)&gdk[(16 * r + fr) * 128];
      acc[r][0] = __builtin_amdgcn_mfma_f32_16x16x32_bf16(a, b0, acc[r][0], 0, 0, 0);
      acc[r][1] = __builtin_amdgcn_mfma_f32_16x16x32_bf16(a, b1, acc[r][1], 0, 0, 0);
    }
  };

  // ---- W3: write dwT + gather tap 0 (private) ------------------------------
  {
    #pragma unroll
    for (int m = 0; m < 2; ++m) {
      uint4 u = { pk2(adw[8*m+0], adw[8*m+1]), pk2(adw[8*m+2], adw[8*m+3]),
                  pk2(adw[8*m+4], adw[8*m+5]), pk2(adw[8*m+6], adw[8*m+7]) };
      *(uint4*)&dwT[(p << 7) + swz(p, cg * 16 + 8 * m)] = u;
    }
    GATHER(0, sbuf0);
  }
  __syncthreads();                            // barrier 3: dwT visible

  // ---- phase C: pointwise 1x1 MFMA + SiLU (oc-split, r11 verbatim) ---------
  f32x4 a4[2][2];
  #pragma unroll
  for (int q1 = 0; q1 < 2; ++q1)
    #pragma unroll
    for (int q2 = 0; q2 < 2; ++q2) a4[q1][q2] = (f32x4){0.f, 0.f, 0.f, 0.f};
  {
    #pragma unroll
    for (int ks = 0; ks < 4; ++ks) {
      int kb = (ks << 5) + (g << 3);
      bf16x8 a0 = *(const bf16x8*)&g_pw[(32 * w + fr) * 128 + kb];
      bf16x8 a1 = *(const bf16x8*)&g_pw[(32 * w + 16 + fr) * 128 + kb];
      #pragma unroll
      for (int tp2 = 0; tp2 < 2; ++tp2) {
        int pp = (tp2 << 4) + fr;
        bf16x8 bb = *(const bf16x8*)&dwT[(pp << 7) + swz(pp, kb)];
        a4[0][tp2] = __builtin_amdgcn_mfma_f32_16x16x32_bf16(a0, bb, a4[0][tp2], 0, 0, 0);
        a4[1][tp2] = __builtin_amdgcn_mfma_f32_16x16x32_bf16(a1, bb, a4[1][tp2], 0, 0, 0);
      }
    }
    #pragma unroll
    for (int toc2 = 0; toc2 < 2; ++toc2)
      #pragma unroll
      for (int tp2 = 0; tp2 < 2; ++tp2)
        #pragma unroll
        for (int reg = 0; reg < 4; ++reg) {
          int oc = 32 * w + 16 * toc2 + 4 * g + reg;
          float v = a4[toc2][tp2][reg] + b_pw[oc];
          a4[toc2][tp2][reg] = v / (1.f + __expf(-v));
        }
  }
  // NOTE: no barrier needed before taps — taps touch only wave-private bufs.

  // ---- phase D: 9 taps, ZERO barriers (wave-private pipeline) --------------
  #pragma unroll 1
  for (int k = 0; k < 9; ++k) {
    uint16_t* rb = (k & 1) ? sbuf1 : sbuf0;
    uint16_t* wb = (k & 1) ? sbuf0 : sbuf1;
    if (k < 8) GATHER(k + 1, wb);        // pipelines under tap-k MFMAs freely
    TAPMM(k, rb);
  }
  __syncthreads();    // all taps done; samp arena dead -> redbuf writable

  // ---- phase R: cross-wave K-reduction (4 serialized phases) ---------------
  #pragma unroll 1
  for (int ph = 0; ph < 4; ++ph) {
    if (w == ph) {
      #pragma unroll
      for (int r = 0; r < 8; ++r)
        #pragma unroll
        for (int tp2 = 0; tp2 < 2; ++tp2)
          #pragma unroll
          for (int reg = 0; reg < 4; ++reg) {
            int oc = 16 * r + g * 4 + reg;
            int px = 16 * tp2 + fr;
            int idx = oc * 33 + px;
            if (ph == 0) redbuf[idx] = acc[r][tp2][reg];
            else         redbuf[idx] += acc[r][tp2][reg];
          }
    }
    __syncthreads();
  }

  // ---- read back oc-split slice + bias (matches r11 epilogue layout) -------
  f32x4 ac1[2][2];
  #pragma unroll
  for (int toc2 = 0; toc2 < 2; ++toc2)
    #pragma unroll
    for (int tp2 = 0; tp2 < 2; ++tp2)
      #pragma unroll
      for (int reg = 0; reg < 4; ++reg) {
        int oc = 32 * w + 16 * toc2 + 4 * g + reg;
        int px = 16 * tp2 + fr;
        ac1[toc2][tp2][reg] = redbuf[oc * 33 + px] + b_def[oc];
      }

  // ---- phase E: LayerNorm + add + store (r11 verbatim) ---------------------
  {
    float s1[2], s2[2];
    #pragma unroll
    for (int tp2 = 0; tp2 < 2; ++tp2) {
      float a = 0.f, q = 0.f;
      #pragma unroll
      for (int toc2 = 0; toc2 < 2; ++toc2)
        #pragma unroll
        for (int reg = 0; reg < 4; ++reg) {
          float v = ac1[toc2][tp2][reg];
          a += v; q += v * v;
        }
      a += __shfl_xor(a, 16); a += __shfl_xor(a, 32);
      q += __shfl_xor(q, 16); q += __shfl_xor(q, 32);
      s1[tp2] = a; s2[tp2] = q;
    }
    __syncthreads();   // redbuf reads done before offarena (red1/red2) reuse
    if (l < 16) {
      red1[w][l] = s1[0]; red1[w][l + 16] = s1[1];
      red2[w][l] = s2[0]; red2[w][l + 16] = s2[1];
    }
  }
  __syncthreads();
  if (t < 32) {
    float m = (red1[0][t] + red1[1][t] + red1[2][t] + red1[3][t]) * (1.f / 128.f);
    float q = (red2[0][t] + red2[1][t] + red2[2][t] + red2[3][t]) * (1.f / 128.f) - m * m;
    muv[t] = m;
    rsv[t] = rsqrtf(q + EPSV);
  }
  __syncthreads();
  {
    #pragma unroll
    for (int toc2 = 0; toc2 < 2; ++toc2)
      #pragma unroll
      for (int tp2 = 0; tp2 < 2; ++tp2) {
        int pp = (tp2 << 4) + fr;
        float mm = muv[pp], rr = rsv[pp];
        #pragma unroll
        for (int reg = 0; reg < 4; ++reg) {
          int oc = 32 * w + 16 * toc2 + 4 * g + reg;
          float v = (ac1[toc2][tp2][reg] - mm) * rr * ln_w[oc] + ln_b[oc]
                    + a4[toc2][tp2][reg];
          out[((size_t)(b * OCN + oc) * HN + h) * WN + w0 + pp] = v;
        }
      }
  }
}

extern "C" void kernel_launch(void* const* d_in, const int* in_sizes, int n_in,
                              void* d_out, int out_size, void* d_ws, size_t ws_size,
                              hipStream_t stream) {
  const float* x     = (const float*)d_in[0];
  const float* w_off = (const float*)d_in[1];
  const float* b_off = (const float*)d_in[2];
  const float* w_def = (const float*)d_in[3];
  const float* b_def = (const float*)d_in[4];
  const float* ln_w  = (const float*)d_in[5];
  const float* ln_b  = (const float*)d_in[6];
  const float* w_dw  = (const float*)d_in[7];
  const float* b_dw  = (const float*)d_in[8];
  const float* w_pw  = (const float*)d_in[9];
  const float* b_pw  = (const float*)d_in[10];
  float* out = (float*)d_out;

  hipLaunchKernelGGL(k_prep_w, dim3(784), dim3(256), 0, stream, w_def, w_pw, w_off);
  hipLaunchKernelGGL(k_prep_x, dim3(BN * HP), dim3(256), 0, stream, x);
  hipLaunchKernelGGL(k_fused, dim3(NWG), dim3(256), 0, stream,
                     b_off, b_def, ln_w, ln_b, w_dw, b_dw, b_pw, out);
}

// Round 18
// 113.953 us; speedup vs baseline: 1.8997x; 1.8997x over previous
//
#include <hip/hip_runtime.h>
#include <hip/hip_bf16.h>
#include <stdint.h>

#define BN 4
#define CN 128
#define HN 96
#define WN 96
#define HW (HN*WN)
#define OCN 128
#define OFFC 18
#define EPSV 1e-6f
#define HP 98
#define WP 98
#define NWG2 (BN*(HN/2)*3)     // 576 blocks: 2 h-rows per block

typedef __attribute__((ext_vector_type(8))) short bf16x8;
typedef __attribute__((ext_vector_type(4))) float f32x4;

__device__ __forceinline__ float lo16(uint32_t u) {
  union { uint32_t i; float f; } v; v.i = u << 16; return v.f;
}
__device__ __forceinline__ float hi16(uint32_t u) {
  union { uint32_t i; float f; } v; v.i = u & 0xffff0000u; return v.f;
}
__device__ __forceinline__ uint16_t f2b(float f) {
  union { float f; uint32_t i; } u; u.f = f;
  uint32_t r = u.i + 0x7fffu + ((u.i >> 16) & 1u);   // RNE
  return (uint16_t)(r >> 16);
}
__device__ __forceinline__ uint32_t pk2(float a, float b) {
  return (uint32_t)f2b(a) | ((uint32_t)f2b(b) << 16);
}
__device__ __forceinline__ int swz(int row, int c) { return c ^ ((row & 7) << 3); }

__device__ __align__(16) uint16_t g_def[9 * 128 * 128];   // [k][oc][c]
__device__ __align__(16) uint16_t g_pw[128 * 128];        // [oc][c]
__device__ __align__(16) uint16_t g_off[32 * 1152];       // [j(pad32)][kk*128+c]
__device__ __align__(16) uint16_t g_xp[(size_t)BN * HP * WP * CN];  // channels-last, padded

__global__ __launch_bounds__(256)
void k_prep_w(const float* __restrict__ w_def, const float* __restrict__ w_pw,
              const float* __restrict__ w_off) {
  int i = blockIdx.x * 256 + threadIdx.x;
  if (i < 147456) {
    int k = i >> 14, rem = i & 16383, oc = rem >> 7, c = rem & 127;
    g_def[i] = f2b(w_def[((oc << 7) + c) * 9 + k]);
  } else if (i < 147456 + 16384) {
    int j = i - 147456;
    g_pw[j] = f2b(w_pw[j]);
  } else if (i < 147456 + 16384 + 36864) {
    int j = i - 163840;
    int row = j / 1152, col = j - row * 1152;
    int kk = col >> 7, c = col & 127;
    g_off[j] = (row < OFFC) ? f2b(w_off[((row << 7) + c) * 9 + kk]) : (uint16_t)0;
  }
}

__global__ __launch_bounds__(256)
void k_prep_x(const float* __restrict__ x) {
  __shared__ uint16_t trans[96][136];
  int blk = blockIdx.x;
  int y1 = blk % HP;
  int b  = blk / HP;
  int t = (int)threadIdx.x;
  uint16_t* dst = g_xp + ((size_t)(b * HP + y1) * WP) * CN;
  if (y1 == 0 || y1 == HP - 1) {
    for (int i = t; i < WP * CN / 8; i += 256)
      ((uint4*)dst)[i] = make_uint4(0, 0, 0, 0);
    return;
  }
  int y = y1 - 1;
  for (int i = t; i < CN * WN / 4; i += 256) {
    int c = i / 24, xq = i - c * 24;
    float4 f = *(const float4*)&x[((size_t)(b * CN + c) * HN + y) * WN + xq * 4];
    trans[xq * 4 + 0][c] = f2b(f.x);
    trans[xq * 4 + 1][c] = f2b(f.y);
    trans[xq * 4 + 2][c] = f2b(f.z);
    trans[xq * 4 + 3][c] = f2b(f.w);
  }
  __syncthreads();
  for (int i = t; i < 2 * CN / 8; i += 256) {
    int side = i >> 4, j = i & 15;
    ((uint4*)(dst + (size_t)side * (WP - 1) * CN))[j] = make_uint4(0, 0, 0, 0);
  }
  for (int i = t; i < WN * CN / 8; i += 256) {
    int xw = i >> 4, cq = (i & 15) * 8;
    ((uint4*)(dst + CN))[i] = *(const uint4*)&trans[xw][cq];
  }
}

// 2 output tiles (rows h, h+1) per block: g_def/g_pw A-fragments amortized 2x.
__global__ __launch_bounds__(256, 2)
void k_fused(const float* __restrict__ b_off, const float* __restrict__ b_def,
             const float* __restrict__ ln_w, const float* __restrict__ ln_b,
             const float* __restrict__ w_dw, const float* __restrict__ b_dw,
             const float* __restrict__ b_pw, float* __restrict__ out) {
  // patch arena: [ky 0..3][i 0..33][128c] swizzled = 17408 u16 (34816B).
  // After barrier 2 (patch dead): dwT = arena[0:8192) (2 tiles x 4096),
  //                               samp = arena[8192:16384) (2 bufs x 4096).
  __shared__ __align__(16) uint16_t patch[4 * 34 * 128];
  // offarena: offl[2][18][32] (1152f) during taps; epilogue red/mu/rs after.
  __shared__ float offarena[1152];

  uint16_t* dwT   = patch;              // +t2*4096
  uint16_t* samp0 = patch + 8192;
  uint16_t* samp1 = patch + 12288;

  int bid = blockIdx.x;
  int wid = (bid & 7) * (NWG2 / 8) + (bid >> 3);   // XCD swizzle (576 = 8*72)
  int wt = wid % 3;
  int h2 = (wid / 3) % (HN / 2);
  int b  = wid / (3 * (HN / 2));
  int h  = 2 * h2;
  int w0 = wt * 32;

  int t = (int)threadIdx.x;
  int l = t & 63, w = t >> 6;
  int g = l >> 4, fr = l & 15;
  int p = t & 31, cg = t >> 5;
  const uint16_t* xb = g_xp + (size_t)b * HP * WP * CN;
  int cbase = w * 32 + (l & 3) * 8;
  const uint16_t* bp = xb + cbase;

  // ---- phase A: stage 4x34 pixel-records -> patch ---------------------------
  #pragma unroll
  for (int rep = 0; rep < 9; ++rep) {
    int e = t + 256 * rep;                    // 2176 chunks
    if (e < 2176) {
      int rec = e >> 4, chunk = e & 15;
      int ky = rec / 34, i = rec - 34 * ky;
      const uint16_t* src = xb + ((size_t)(h + ky) * WP + (w0 + i)) * CN + chunk * 8;
      *(uint4*)&patch[((ky * 34 + i) << 7) + swz(i, chunk * 8)] = *(const uint4*)src;
    }
  }
  __syncthreads();                            // barrier 1

  // ---- phase B1: offsets conv MFMA; waves 0,1->tile0, 2,3->tile1 ------------
  {
    int t1 = w >> 1, toc = w & 1;
    f32x4 aco0 = {0.f,0.f,0.f,0.f}, aco1 = {0.f,0.f,0.f,0.f};
    #pragma unroll
    for (int ks = 0; ks < 36; ++ks) {
      int kk = ks >> 2;
      int ky = kk / 3, kx = kk - 3 * ky;
      int cb = ((ks & 3) << 5) + (g << 3);
      bf16x8 a = *(const bf16x8*)&g_off[(toc * 16 + fr) * 1152 + (ks << 5) + (g << 3)];
      int i0 = fr + kx, i1 = fr + 16 + kx;
      bf16x8 bb0 = *(const bf16x8*)&patch[(((t1 + ky) * 34 + i0) << 7) + swz(i0, cb)];
      bf16x8 bb1 = *(const bf16x8*)&patch[(((t1 + ky) * 34 + i1) << 7) + swz(i1, cb)];
      aco0 = __builtin_amdgcn_mfma_f32_16x16x32_bf16(a, bb0, aco0, 0, 0, 0);
      aco1 = __builtin_amdgcn_mfma_f32_16x16x32_bf16(a, bb1, aco1, 0, 0, 0);
    }
    #pragma unroll
    for (int reg = 0; reg < 4; ++reg) {
      int j = toc * 16 + g * 4 + reg;
      if (j < OFFC) {
        offarena[t1 * 576 + j * 32 + fr]      = aco0[reg] + b_off[j];
        offarena[t1 * 576 + j * 32 + 16 + fr] = aco1[reg] + b_off[j];
      }
    }
  }

  // ---- phase B2: depthwise 3x3 + residual for both tiles -> regs ------------
  float adw0[16], adw1[16];
  auto DW = [&](float (&A)[16], int t2) {
    #pragma unroll
    for (int cl = 0; cl < 16; ++cl) A[cl] = b_dw[cg * 16 + cl];
    #pragma unroll
    for (int ky = 0; ky < 3; ++ky) {
      #pragma unroll
      for (int kx = 0; kx < 3; ++kx) {
        int i = p + kx, row = t2 + ky;
        uint32_t r[8];
        *(uint4*)&r[0] = *(const uint4*)&patch[((row * 34 + i) << 7) + swz(i, cg * 16)];
        *(uint4*)&r[4] = *(const uint4*)&patch[((row * 34 + i) << 7) + swz(i, cg * 16 + 8)];
        #pragma unroll
        for (int c2 = 0; c2 < 8; ++c2) {
          A[2 * c2]     += lo16(r[c2]) * w_dw[(cg * 16 + 2 * c2) * 9 + ky * 3 + kx];
          A[2 * c2 + 1] += hi16(r[c2]) * w_dw[(cg * 16 + 2 * c2 + 1) * 9 + ky * 3 + kx];
        }
      }
    }
    int i = p + 1, row = t2 + 1;
    uint32_t r[8];
    *(uint4*)&r[0] = *(const uint4*)&patch[((row * 34 + i) << 7) + swz(i, cg * 16)];
    *(uint4*)&r[4] = *(const uint4*)&patch[((row * 34 + i) << 7) + swz(i, cg * 16 + 8)];
    #pragma unroll
    for (int c2 = 0; c2 < 8; ++c2) {
      A[2 * c2]     += lo16(r[c2]);
      A[2 * c2 + 1] += hi16(r[c2]);
    }
  };
  DW(adw0, 0);
  DW(adw1, 1);
  __syncthreads();    // barrier 2: patch dead -> dwT/samp aliases writable

  // gather tap kk of tile t2 -> wb (r11-proven shape; offl/ys depend on t2)
  auto GATHER = [&](int kk, int t2, uint16_t* wb) {
    int ky = kk / 3, kx = kk - 3 * ky;
    #pragma unroll
    for (int half = 0; half < 2; ++half) {
      int px = half * 16 + (l >> 2);
      float dy = offarena[t2 * 576 + (2 * kk) * 32 + px];
      float dx = offarena[t2 * 576 + (2 * kk + 1) * 32 + px];
      float ys = (float)(h + t2 - 1 + ky) + dy;
      float xs = (float)(w0 + px - 1 + kx) + dx;
      float y0f = floorf(ys), x0f = floorf(xs);
      float fy = ys - y0f, fx = xs - x0f;
      int y0 = (int)y0f, x0 = (int)x0f;
      float w00 = (1.f - fy) * (1.f - fx), w01 = (1.f - fy) * fx;
      float w10 = fy * (1.f - fx),         w11 = fy * fx;
      bool yok0 = (y0 >= 0) & (y0 < HN), yok1 = (y0 + 1 >= 0) & (y0 + 1 < HN);
      bool xok0 = (x0 >= 0) & (x0 < WN), xok1 = (x0 + 1 >= 0) & (x0 + 1 < WN);
      if (!(yok0 & xok0)) w00 = 0.f;
      if (!(yok0 & xok1)) w01 = 0.f;
      if (!(yok1 & xok0)) w10 = 0.f;
      if (!(yok1 & xok1)) w11 = 0.f;
      int ya  = min(max(y0, -1), HN) + 1;
      int yb2 = min(max(y0 + 1, -1), HN) + 1;
      int xa  = min(max(x0, -1), WN) + 1;
      int xc2 = min(max(x0 + 1, -1), WN) + 1;
      uint32_t A[4], B[4], C[4], D[4];
      *(uint4*)A = *(const uint4*)(bp + ((size_t)ya * WP + xa) * CN);
      *(uint4*)B = *(const uint4*)(bp + ((size_t)ya * WP + xc2) * CN);
      *(uint4*)C = *(const uint4*)(bp + ((size_t)yb2 * WP + xa) * CN);
      *(uint4*)D = *(const uint4*)(bp + ((size_t)yb2 * WP + xc2) * CN);
      uint32_t pk4[4];
      #pragma unroll
      for (int q2 = 0; q2 < 4; ++q2) {
        float s0 = w00 * lo16(A[q2]) + w01 * lo16(B[q2]) + w10 * lo16(C[q2]) + w11 * lo16(D[q2]);
        float s1 = w00 * hi16(A[q2]) + w01 * hi16(B[q2]) + w10 * hi16(C[q2]) + w11 * hi16(D[q2]);
        pk4[q2] = pk2(s0, s1);
      }
      *(uint4*)&wb[(px << 7) + swz(px, cbase)] = *(uint4*)pk4;
    }
  };

  // ---- W3: write dwT (both tiles) + gather step 0 (tap0, tile0) -------------
  {
    #pragma unroll
    for (int m = 0; m < 2; ++m) {
      uint4 u0 = { pk2(adw0[8*m+0], adw0[8*m+1]), pk2(adw0[8*m+2], adw0[8*m+3]),
                   pk2(adw0[8*m+4], adw0[8*m+5]), pk2(adw0[8*m+6], adw0[8*m+7]) };
      *(uint4*)&dwT[(p << 7) + swz(p, cg * 16 + 8 * m)] = u0;
      uint4 u1 = { pk2(adw1[8*m+0], adw1[8*m+1]), pk2(adw1[8*m+2], adw1[8*m+3]),
                   pk2(adw1[8*m+4], adw1[8*m+5]), pk2(adw1[8*m+6], adw1[8*m+7]) };
      *(uint4*)&dwT[4096 + (p << 7) + swz(p, cg * 16 + 8 * m)] = u1;
    }
    GATHER(0, 0, samp0);
  }
  __syncthreads();                            // barrier 3

  // ---- phase C: pointwise MFMA + SiLU, A-frags shared across tiles ----------
  f32x4 a4T0[2][2], a4T1[2][2];
  #pragma unroll
  for (int q1 = 0; q1 < 2; ++q1)
    #pragma unroll
    for (int q2 = 0; q2 < 2; ++q2) {
      a4T0[q1][q2] = (f32x4){0.f,0.f,0.f,0.f};
      a4T1[q1][q2] = (f32x4){0.f,0.f,0.f,0.f};
    }
  {
    #pragma unroll
    for (int ks = 0; ks < 4; ++ks) {
      int kb = (ks << 5) + (g << 3);
      bf16x8 p0 = *(const bf16x8*)&g_pw[(32 * w + fr) * 128 + kb];
      bf16x8 p1 = *(const bf16x8*)&g_pw[(32 * w + 16 + fr) * 128 + kb];
      #pragma unroll
      for (int tp2 = 0; tp2 < 2; ++tp2) {
        int pp = (tp2 << 4) + fr;
        bf16x8 bb0 = *(const bf16x8*)&dwT[(pp << 7) + swz(pp, kb)];
        bf16x8 bb1 = *(const bf16x8*)&dwT[4096 + (pp << 7) + swz(pp, kb)];
        a4T0[0][tp2] = __builtin_amdgcn_mfma_f32_16x16x32_bf16(p0, bb0, a4T0[0][tp2], 0, 0, 0);
        a4T0[1][tp2] = __builtin_amdgcn_mfma_f32_16x16x32_bf16(p1, bb0, a4T0[1][tp2], 0, 0, 0);
        a4T1[0][tp2] = __builtin_amdgcn_mfma_f32_16x16x32_bf16(p0, bb1, a4T1[0][tp2], 0, 0, 0);
        a4T1[1][tp2] = __builtin_amdgcn_mfma_f32_16x16x32_bf16(p1, bb1, a4T1[1][tp2], 0, 0, 0);
      }
    }
    auto SILU = [&](f32x4 (&A)[2][2]) {
      #pragma unroll
      for (int toc2 = 0; toc2 < 2; ++toc2)
        #pragma unroll
        for (int tp2 = 0; tp2 < 2; ++tp2)
          #pragma unroll
          for (int reg = 0; reg < 4; ++reg) {
            int oc = 32 * w + 16 * toc2 + 4 * g + reg;
            float v = A[toc2][tp2][reg] + b_pw[oc];
            A[toc2][tp2][reg] = v / (1.f + __expf(-v));
          }
    };
    SILU(a4T0); SILU(a4T1);
  }
  __syncthreads();                            // barrier 4

  // ---- phase D: 18 steps (tap x tile); af loaded once per tap ---------------
  f32x4 acT0[2][2], acT1[2][2];
  #pragma unroll
  for (int q1 = 0; q1 < 2; ++q1)
    #pragma unroll
    for (int q2 = 0; q2 < 2; ++q2) {
      acT0[q1][q2] = (f32x4){0.f,0.f,0.f,0.f};
      acT1[q1][q2] = (f32x4){0.f,0.f,0.f,0.f};
    }
  bf16x8 af0[4], af1[4];
  auto MM = [&](f32x4 (&A)[2][2], const uint16_t* rb) {
    #pragma unroll
    for (int ks = 0; ks < 4; ++ks) {
      int kb = (ks << 5) + (g << 3);
      #pragma unroll
      for (int tp2 = 0; tp2 < 2; ++tp2) {
        int pp = (tp2 << 4) + fr;
        bf16x8 bb = *(const bf16x8*)&rb[(pp << 7) + swz(pp, kb)];
        A[0][tp2] = __builtin_amdgcn_mfma_f32_16x16x32_bf16(af0[ks], bb, A[0][tp2], 0, 0, 0);
        A[1][tp2] = __builtin_amdgcn_mfma_f32_16x16x32_bf16(af1[ks], bb, A[1][tp2], 0, 0, 0);
      }
    }
  };

  #pragma unroll 1
  for (int s = 0; s < 18; ++s) {
    int k = s >> 1;
    uint16_t* rb = (s & 1) ? samp1 : samp0;
    uint16_t* wb = (s & 1) ? samp0 : samp1;
    if (s < 17) {
      int sn = s + 1;
      GATHER(sn >> 1, sn & 1, wb);            // loads overlap this step's MFMAs
    }
    if ((s & 1) == 0) {
      const uint16_t* gdk = g_def + (k << 14);
      #pragma unroll
      for (int ks = 0; ks < 4; ++ks) {
        int kb = (ks << 5) + (g << 3);
        af0[ks] = *(const bf16x8*)&gdk[(32 * w + fr) * 128 + kb];
        af1[ks] = *(const bf16x8*)&gdk[(32 * w + 16 + fr) * 128 + kb];
      }
      MM(acT0, rb);
    } else {
      MM(acT1, rb);                           // af reused: g_def amortized 2x
    }
    __syncthreads();
  }

  // ---- epilogue: bias + LN + add + store, both tiles -------------------------
  auto ADDB = [&](f32x4 (&A)[2][2]) {
    #pragma unroll
    for (int toc2 = 0; toc2 < 2; ++toc2)
      #pragma unroll
      for (int tp2 = 0; tp2 < 2; ++tp2)
        #pragma unroll
        for (int reg = 0; reg < 4; ++reg)
          A[toc2][tp2][reg] += b_def[32 * w + 16 * toc2 + 4 * g + reg];
  };
  ADDB(acT0); ADDB(acT1);

  auto SUMS = [&](f32x4 (&A)[2][2], int t2) {
    #pragma unroll
    for (int tp2 = 0; tp2 < 2; ++tp2) {
      float a = 0.f, q = 0.f;
      #pragma unroll
      for (int toc2 = 0; toc2 < 2; ++toc2)
        #pragma unroll
        for (int reg = 0; reg < 4; ++reg) {
          float v = A[toc2][tp2][reg];
          a += v; q += v * v;
        }
      a += __shfl_xor(a, 16); a += __shfl_xor(a, 32);
      q += __shfl_xor(q, 16); q += __shfl_xor(q, 32);
      if (l < 16) {
        float* r1 = offarena + t2 * 256;
        float* r2 = r1 + 128;
        r1[w * 32 + l + 16 * tp2] = a;
        r2[w * 32 + l + 16 * tp2] = q;
      }
    }
  };
  SUMS(acT0, 0); SUMS(acT1, 1);
  __syncthreads();
  if (t < 64) {
    int tt = t >> 5, px = t & 31;
    float* r1 = offarena + tt * 256;
    float* r2 = r1 + 128;
    float m = (r1[px] + r1[32 + px] + r1[64 + px] + r1[96 + px]) * (1.f / 128.f);
    float q = (r2[px] + r2[32 + px] + r2[64 + px] + r2[96 + px]) * (1.f / 128.f) - m * m;
    offarena[512 + tt * 32 + px] = m;
    offarena[576 + tt * 32 + px] = rsqrtf(q + EPSV);
  }
  __syncthreads();

  auto STORE = [&](f32x4 (&A)[2][2], f32x4 (&P)[2][2], int t2) {
    #pragma unroll
    for (int toc2 = 0; toc2 < 2; ++toc2)
      #pragma unroll
      for (int tp2 = 0; tp2 < 2; ++tp2) {
        int pp = (tp2 << 4) + fr;
        float mm = offarena[512 + t2 * 32 + pp];
        float rr = offarena[576 + t2 * 32 + pp];
        #pragma unroll
        for (int reg = 0; reg < 4; ++reg) {
          int oc = 32 * w + 16 * toc2 + 4 * g + reg;
          float v = (A[toc2][tp2][reg] - mm) * rr * ln_w[oc] + ln_b[oc]
                    + P[toc2][tp2][reg];
          out[((size_t)(b * OCN + oc) * HN + h + t2) * WN + w0 + pp] = v;
        }
      }
  };
  STORE(acT0, a4T0, 0);
  STORE(acT1, a4T1, 1);
}

extern "C" void kernel_launch(void* const* d_in, const int* in_sizes, int n_in,
                              void* d_out, int out_size, void* d_ws, size_t ws_size,
                              hipStream_t stream) {
  const float* x     = (const float*)d_in[0];
  const float* w_off = (const float*)d_in[1];
  const float* b_off = (const float*)d_in[2];
  const float* w_def = (const float*)d_in[3];
  const float* b_def = (const float*)d_in[4];
  const float* ln_w  = (const float*)d_in[5];
  const float* ln_b  = (const float*)d_in[6];
  const float* w_dw  = (const float*)d_in[7];
  const float* b_dw  = (const float*)d_in[8];
  const float* w_pw  = (const float*)d_in[9];
  const float* b_pw  = (const float*)d_in[10];
  float* out = (float*)d_out;

  hipLaunchKernelGGL(k_prep_w, dim3(784), dim3(256), 0, stream, w_def, w_pw, w_off);
  hipLaunchKernelGGL(k_prep_x, dim3(BN * HP), dim3(256), 0, stream, x);
  hipLaunchKernelGGL(k_fused, dim3(NWG2), dim3(256), 0, stream,
                     b_off, b_def, ln_w, ln_b, w_dw, b_dw, b_pw, out);
}